// Round 7
// baseline (98.281 us; speedup 1.0000x reference)
//
#include <hip/hip_runtime.h>
#include <hip/hip_bf16.h>

// Glow coupling layer, fused. rows N = 262144, C = 64.
// r2 = MLP_s2(x2); y1 = e(s2)*x1 + t2; r1 = MLP_s1(y1); y2 = e(s1)*x2 + t1.
//
// Round 7: R5 4-wave f-split (weights register-resident per layer) +
//  - PINNED weight frags (asm "+v") so the allocator can't sink/remat loads
//  - h buffers [64][256B] + XOR (r&7)<<4: bank-balanced b64 W / b128 R
//  - interleaved W3 permutation: lane regs = {s_f0,s_f1,t_f0,t_f1} -> in-lane
//    epilogue (8 e_fun/lane/epi, no shuffles, no duplicate work, float2 out)
//  - L1 x2-fragments straight from global (L2-hot dup, no staging barrier)
//  - 6 barriers total; LDS 32KB; LB(256,4)
//
// MFMA v_mfma_f32_16x16x32_bf16, W = A-operand, activations = B-operand:
//   A frag: lane l holds A[row=l&15][k=(l>>4)*8+j]
//   B frag: lane l holds B[k=(l>>4)*8+j][col=l&15]
//   D     : lane l reg i -> (A-row = 4*(l>>4)+i, col = l&15)  [m89/m91]

using bf16x8 = __attribute__((ext_vector_type(8))) short;
using f32x4  = __attribute__((ext_vector_type(4))) float;
using u32x2  = __attribute__((ext_vector_type(2))) unsigned int;

#define PIN(v) asm volatile("" : "+v"(v))

__device__ __forceinline__ unsigned short f2bf(float f) {
    unsigned int u = __float_as_uint(f);
    u += 0x7FFFu + ((u >> 16) & 1u);
    return (unsigned short)(u >> 16);
}
__device__ __forceinline__ unsigned int pk2bf(float a, float b) {
    union { __hip_bfloat162 h; unsigned int u; } cv;
    cv.h = __float22bfloat162_rn(float2{a, b});
    return cv.u;   // low16 = bf16(a), high16 = bf16(b)
}
__device__ __forceinline__ float lo16f(unsigned int u) { return __uint_as_float(u << 16); }
__device__ __forceinline__ float hi16f(unsigned int u) { return __uint_as_float(u & 0xFFFF0000u); }

__device__ __forceinline__ f32x4 mfma16(bf16x8 a, bf16x8 b, f32x4 c) {
    return __builtin_amdgcn_mfma_f32_16x16x32_bf16(a, b, c, 0, 0, 0);
}

// e(s) = exp(3.18*atan(s/5)) = exp2(4.5877702*atan(0.2 s)); deg-11 minimax.
__device__ __forceinline__ float e_fun(float s) {
    float z = 0.2f * s;
    float a = fabsf(z);
    float t = fminf(a, __builtin_amdgcn_rcpf(a));   // a<=1 ? a : 1/a
    float u = t * t;
    float p = -0.0537741f;
    p = fmaf(p, u,  0.2415614f);
    p = fmaf(p, u, -0.5341673f);
    p = fmaf(p, u,  0.8879339f);
    p = fmaf(p, u, -1.5260000f);
    p = fmaf(p, u,  4.5876659f);
    p = p * t;
    float r = (a > 1.0f) ? (7.2064613f - p) : p;    // K*pi/2 - p
    r = copysignf(r, s);
    return __builtin_amdgcn_exp2f(r);
}

// W3 interleaved permutation: wave w, frag-row fr = 4q+i ->
//   i<2: s-feature 8w+2q+i ; i>=2: t-feature 32+8w+2q+(i-2)
__device__ __forceinline__ int feat3b(int w, int fr) {
    int q = fr >> 2, i = fr & 3;
    int base = 8 * w + 2 * q;
    return (i < 2) ? (base + i) : (32 + base + (i - 2));
}

// LDS: h1 [64][256B] @0 (16384); h2 [64][256B] @16384.
// y1 planes (hi [64][80B] + lo) time-share h2[0:10240].
#define LDS_BYTES 32768

#define BIAS_OFF 114688           // 112 tiles * 1024B
#define WS_NEED  (114688 + 2560)

struct WPtrs { const float *w1, *b1, *w2, *b2, *w3, *b3; };

__device__ __forceinline__ bf16x8 load_wfrag(const float* __restrict__ W, int K, int frow, int k0) {
    const float4* p = reinterpret_cast<const float4*>(W + (size_t)frow * K + k0);
    float4 a = p[0], b = p[1];
    bf16x8 r;
    r[0] = (short)f2bf(a.x); r[1] = (short)f2bf(a.y);
    r[2] = (short)f2bf(a.z); r[3] = (short)f2bf(a.w);
    r[4] = (short)f2bf(b.x); r[5] = (short)f2bf(b.y);
    r[6] = (short)f2bf(b.z); r[7] = (short)f2bf(b.w);
    return r;
}

template<int MODE>
__device__ __forceinline__ bf16x8 get_frag(const char* wsb, const WPtrs& P, int mlp,
                                           int tile, int which, int row, int k0, int lane) {
    if constexpr (MODE != 0) {
        union { uint4 q; bf16x8 v; } u;
        u.q = reinterpret_cast<const uint4*>(wsb)[(mlp * 56 + tile) * 64 + lane];
        return u.v;
    } else {
        const float* W = (which == 0) ? P.w1 : (which == 1) ? P.w2 : P.w3;
        return load_wfrag(W, (which == 0) ? 32 : 128, row, k0);
    }
}

__device__ __forceinline__ f32x4 ld4(const float* p) {
    return *reinterpret_cast<const f32x4*>(p);
}

// ---- one 3-layer MLP over the 64-row tile, 4-wave f-split ----
// SRC=0: L1 input = x2 from global (gx = x + rowbase*64).
// SRC=1: L1 input = y1 hi/lo planes in LDS (ph/pl, pitch 80B).
// rr[m] regs: i<2 -> s at col 8w+2lg+i ; i>=2 -> t at col 8w+2lg+(i-2).
template<int MODE, int SRC>
__device__ __forceinline__ void run_mlp(
    const char* __restrict__ wsb, const WPtrs& P, int mlp,
    const float* __restrict__ gx,
    const char* __restrict__ ph, const char* __restrict__ pl,
    char* __restrict__ h1, char* __restrict__ h2,
    int w, int lg, int lr, int lane, f32x4 (&rr)[4])
{
    const int sw = (lr & 7) << 4;
    const float* bias = reinterpret_cast<const float*>(wsb + BIAS_OFF) + mlp * 320;

    // ---------- layer 1: K=32 (hi+lo), wave's tiles ft = 2w, 2w+1 ----------
    bf16x8 wb1[2]; f32x4 b1v[2];
    #pragma unroll
    for (int f = 0; f < 2; ++f) {
        const int ft = 2 * w + f;
        wb1[f] = get_frag<MODE>(wsb, P, mlp, ft, 0, 16 * ft + lr, 8 * lg, lane);
        PIN(wb1[f]);
        b1v[f] = MODE ? ld4(bias + 16 * ft + 4 * lg) : ld4(P.b1 + 16 * ft + 4 * lg);
        PIN(b1v[f]);
    }
    #pragma unroll
    for (int m = 0; m < 4; ++m) {
        const int r = 16 * m + lr;
        bf16x8 bh, bl;
        if constexpr (SRC == 0) {
            const float* xp = gx + (size_t)r * 64 + 32 + 8 * lg;
            f32x4 xa = ld4(xp), xb = ld4(xp + 4);
            union FB { bf16x8 v; unsigned int u[4]; } H, L;
            H.u[0] = pk2bf(xa[0], xa[1]);  H.u[1] = pk2bf(xa[2], xa[3]);
            H.u[2] = pk2bf(xb[0], xb[1]);  H.u[3] = pk2bf(xb[2], xb[3]);
            L.u[0] = pk2bf(xa[0] - lo16f(H.u[0]), xa[1] - hi16f(H.u[0]));
            L.u[1] = pk2bf(xa[2] - lo16f(H.u[1]), xa[3] - hi16f(H.u[1]));
            L.u[2] = pk2bf(xb[0] - lo16f(H.u[2]), xb[1] - hi16f(H.u[2]));
            L.u[3] = pk2bf(xb[2] - lo16f(H.u[3]), xb[3] - hi16f(H.u[3]));
            bh = H.v; bl = L.v;
        } else {
            bh = *reinterpret_cast<const bf16x8*>(ph + r * 80 + 16 * lg);
            bl = *reinterpret_cast<const bf16x8*>(pl + r * 80 + 16 * lg);
        }
        #pragma unroll
        for (int f = 0; f < 2; ++f) {
            f32x4 acc = b1v[f];
            acc = mfma16(wb1[f], bh, acc);
            acc = mfma16(wb1[f], bl, acc);
            u32x2 pp = { pk2bf(fmaxf(acc[0], 0.f), fmaxf(acc[1], 0.f)),
                         pk2bf(fmaxf(acc[2], 0.f), fmaxf(acc[3], 0.f)) };
            *reinterpret_cast<u32x2*>(h1 + r * 256 + ((32 * (2 * w + f) + 8 * lg) ^ sw)) = pp;
        }
    }
    __syncthreads();

    // ---------- layer 2: K=128 ----------
    bf16x8 wb2[2][4]; f32x4 b2v[2];
    #pragma unroll
    for (int f = 0; f < 2; ++f) {
        const int ft = 2 * w + f;
        #pragma unroll
        for (int ks = 0; ks < 4; ++ks) {
            wb2[f][ks] = get_frag<MODE>(wsb, P, mlp, 8 + ft * 4 + ks, 1,
                                        16 * ft + lr, 32 * ks + 8 * lg, lane);
            PIN(wb2[f][ks]);
        }
        b2v[f] = MODE ? ld4(bias + 128 + 16 * ft + 4 * lg) : ld4(P.b2 + 16 * ft + 4 * lg);
        PIN(b2v[f]);
    }
    #pragma unroll
    for (int m = 0; m < 4; ++m) {
        const int r = 16 * m + lr;
        bf16x8 hf[4];
        #pragma unroll
        for (int ks = 0; ks < 4; ++ks)
            hf[ks] = *reinterpret_cast<const bf16x8*>(h1 + r * 256 + ((64 * ks + 16 * lg) ^ sw));
        #pragma unroll
        for (int f = 0; f < 2; ++f) {
            f32x4 acc = b2v[f];
            #pragma unroll
            for (int ks = 0; ks < 4; ++ks)
                acc = mfma16(wb2[f][ks], hf[ks], acc);
            u32x2 pp = { pk2bf(fmaxf(acc[0], 0.f), fmaxf(acc[1], 0.f)),
                         pk2bf(fmaxf(acc[2], 0.f), fmaxf(acc[3], 0.f)) };
            *reinterpret_cast<u32x2*>(h2 + r * 256 + ((32 * (2 * w + f) + 8 * lg) ^ sw)) = pp;
        }
    }
    __syncthreads();

    // ---------- layer 3: K=128, interleaved s/t features ----------
    bf16x8 wb3[4];
    #pragma unroll
    for (int ks = 0; ks < 4; ++ks) {
        wb3[ks] = get_frag<MODE>(wsb, P, mlp, 40 + 4 * w + ks, 2,
                                 feat3b(w, lr), 32 * ks + 8 * lg, lane);
        PIN(wb3[ks]);
    }
    f32x4 b3v;
    if (MODE) {
        b3v = ld4(bias + 256 + 16 * w + 4 * lg);
    } else {
        float2 sa = *reinterpret_cast<const float2*>(P.b3 + 8 * w + 2 * lg);
        float2 sb = *reinterpret_cast<const float2*>(P.b3 + 32 + 8 * w + 2 * lg);
        b3v = f32x4{sa.x, sa.y, sb.x, sb.y};
    }
    PIN(b3v);
    #pragma unroll
    for (int m = 0; m < 4; ++m) {
        const int r = 16 * m + lr;
        f32x4 acc = b3v;
        #pragma unroll
        for (int ks = 0; ks < 4; ++ks) {
            bf16x8 hg = *reinterpret_cast<const bf16x8*>(h2 + r * 256 + ((64 * ks + 16 * lg) ^ sw));
            acc = mfma16(wb3[ks], hg, acc);
        }
        rr[m] = acc;
    }
}

// ---- weight prep: fragment tiles (1KB each) + biases (b3 permuted) ----
extern "C" __global__ void __launch_bounds__(256)
glow_prep(const float* __restrict__ s2w1, const float* __restrict__ s2w2,
          const float* __restrict__ s2w3, const float* __restrict__ s1w1,
          const float* __restrict__ s1w2, const float* __restrict__ s1w3,
          const float* __restrict__ s2b1, const float* __restrict__ s2b2,
          const float* __restrict__ s2b3, const float* __restrict__ s1b1,
          const float* __restrict__ s1b2, const float* __restrict__ s1b3,
          char* __restrict__ wsb)
{
    const int wave = threadIdx.x >> 6, lane = threadIdx.x & 63;
    const int lr = lane & 15, lg = lane >> 4;
    const int gw = blockIdx.x * 4 + wave;

    if (gw < 112) {
        int mlp = gw / 56, t = gw % 56;
        const float* Ws[2][3] = {{s2w1, s2w2, s2w3}, {s1w1, s1w2, s1w3}};
        const float* W; int K, row, k0;
        if (t < 8)       { W = Ws[mlp][0]; K = 32;  row = 16 * t + lr;          k0 = lg * 8; }
        else if (t < 40) { int u = t - 8;  W = Ws[mlp][1]; K = 128; row = 16 * (u >> 2) + lr; k0 = 32 * (u & 3) + lg * 8; }
        else             { int u = t - 40; W = Ws[mlp][2]; K = 128; row = feat3b(u >> 2, lr); k0 = 32 * (u & 3) + lg * 8; }
        const float* p = W + (size_t)row * K + k0;
        union U { uint4 q; bf16x8 v; } u;
        #pragma unroll
        for (int j = 0; j < 8; ++j) u.v[j] = (short)f2bf(p[j]);
        reinterpret_cast<uint4*>(wsb)[gw * 64 + lane] = u.q;
    } else if (blockIdx.x == 28) {
        const float* Bs[2][3] = {{s2b1, s2b2, s2b3}, {s1b1, s1b2, s1b3}};
        float* dst = reinterpret_cast<float*>(wsb + BIAS_OFF);
        for (int i = threadIdx.x; i < 640; i += 256) {
            int mlp = i / 320, j = i % 320;
            float v;
            if (j < 128)      v = Bs[mlp][0][j];
            else if (j < 256) v = Bs[mlp][1][j - 128];
            else { int k = j - 256; v = Bs[mlp][2][feat3b(k >> 4, k & 15)]; }
            dst[i] = v;
        }
    }
}

template<int MODE>
__global__ void __launch_bounds__(256, 4)
glow_main(const float* __restrict__ x,
          const float* __restrict__ s1w1, const float* __restrict__ s1b1,
          const float* __restrict__ s1w2, const float* __restrict__ s1b2,
          const float* __restrict__ s1w3, const float* __restrict__ s1b3,
          const float* __restrict__ s2w1, const float* __restrict__ s2b1,
          const float* __restrict__ s2w2, const float* __restrict__ s2b2,
          const float* __restrict__ s2w3, const float* __restrict__ s2b3,
          const char* __restrict__ wsb, float* __restrict__ out)
{
    __shared__ __align__(16) char lds[LDS_BYTES];
    char* h1 = lds;
    char* h2 = lds + 16384;
    char* ph = h2;             // y1 planes hi [64][80B], time-share h2
    char* pl = h2 + 5120;      // y1 planes lo

    const int tid  = threadIdx.x;
    const int w = tid >> 6, lane = tid & 63;
    const int lr = lane & 15, lg = lane >> 4;
    const size_t rowbase = (size_t)blockIdx.x * 64;
    const float* gx = x   + rowbase * 64;
    float*       go = out + rowbase * 64;

    const WPtrs P0 = {s2w1, s2b1, s2w2, s2b2, s2w3, s2b3};
    const WPtrs P1 = {s1w1, s1b1, s1w2, s1b2, s1w3, s1b3};

    const int c0 = 8 * w + 2 * lg;
    f32x4 rr[4];

    // ---- MLP s2 on x2 (2 internal barriers) ----
    run_mlp<MODE, 0>(wsb, P0, 0, gx, ph, pl, h1, h2, w, lg, lr, lane, rr);
    __syncthreads();   // h2 (L3) reads done before plane writes

    // ---- epilogue 1: y1 = e(s2)*x1 + t2 -> out cols 0..31 + y1 planes ----
    #pragma unroll
    for (int m = 0; m < 4; ++m) {
        const int r = 16 * m + lr;
        float2 xv = *reinterpret_cast<const float2*>(gx + (size_t)r * 64 + c0);
        float y0 = fmaf(e_fun(rr[m][0]), xv.x, rr[m][2]);
        float y1 = fmaf(e_fun(rr[m][1]), xv.y, rr[m][3]);
        *reinterpret_cast<float2*>(go + (size_t)r * 64 + c0) = float2{y0, y1};
        unsigned int hh = pk2bf(y0, y1);
        unsigned int ll = pk2bf(y0 - lo16f(hh), y1 - hi16f(hh));
        *reinterpret_cast<unsigned int*>(ph + r * 80 + 2 * c0) = hh;
        *reinterpret_cast<unsigned int*>(pl + r * 80 + 2 * c0) = ll;
    }
    __syncthreads();   // planes visible to all waves

    // ---- MLP s1 on y1 (2 internal barriers) ----
    run_mlp<MODE, 1>(wsb, P1, 1, gx, ph, pl, h1, h2, w, lg, lr, lane, rr);

    // ---- epilogue 2: y2 = e(s1)*x2 + t1 -> out cols 32..63 (no LDS) ----
    #pragma unroll
    for (int m = 0; m < 4; ++m) {
        const int r = 16 * m + lr;
        float2 xv = *reinterpret_cast<const float2*>(gx + (size_t)r * 64 + 32 + c0);
        float y0 = fmaf(e_fun(rr[m][0]), xv.x, rr[m][2]);
        float y1 = fmaf(e_fun(rr[m][1]), xv.y, rr[m][3]);
        *reinterpret_cast<float2*>(go + (size_t)r * 64 + 32 + c0) = float2{y0, y1};
    }
}

extern "C" void kernel_launch(void* const* d_in, const int* in_sizes, int n_in,
                              void* d_out, int out_size, void* d_ws, size_t ws_size,
                              hipStream_t stream) {
    const float* x    = (const float*)d_in[0];
    const float* s1w1 = (const float*)d_in[1];
    const float* s1b1 = (const float*)d_in[2];
    const float* s1w2 = (const float*)d_in[3];
    const float* s1b2 = (const float*)d_in[4];
    const float* s1w3 = (const float*)d_in[5];
    const float* s1b3 = (const float*)d_in[6];
    const float* s2w1 = (const float*)d_in[7];
    const float* s2b1 = (const float*)d_in[8];
    const float* s2w2 = (const float*)d_in[9];
    const float* s2b2 = (const float*)d_in[10];
    const float* s2w3 = (const float*)d_in[11];
    const float* s2b3 = (const float*)d_in[12];
    float* out = (float*)d_out;
    char* wsb  = (char*)d_ws;

    int nrows   = in_sizes[0] / 64;   // 262144
    int nblocks = nrows / 64;         // 4096

    if (ws_size >= (size_t)WS_NEED) {
        hipLaunchKernelGGL(glow_prep, dim3(29), dim3(256), 0, stream,
                           s2w1, s2w2, s2w3, s1w1, s1w2, s1w3,
                           s2b1, s2b2, s2b3, s1b1, s1b2, s1b3, wsb);
        hipLaunchKernelGGL((glow_main<1>), dim3(nblocks), dim3(256), 0, stream,
                           x, s1w1, s1b1, s1w2, s1b2, s1w3, s1b3,
                           s2w1, s2b1, s2w2, s2b2, s2w3, s2b3, wsb, out);
    } else {
        hipLaunchKernelGGL((glow_main<0>), dim3(nblocks), dim3(256), 0, stream,
                           x, s1w1, s1b1, s1w2, s1b2, s1w3, s1b3,
                           s2w1, s2b1, s2w2, s2b2, s2w3, s2b3, wsb, out);
    }
}

// Round 8
// 69.016 us; speedup vs baseline: 1.4240x; 1.4240x over previous
//
#include <hip/hip_runtime.h>
#include <hip/hip_bf16.h>

// Glow coupling layer, fused. rows N = 262144, C = 64.
// r2 = MLP_s2(x2); y1 = e(s2)*x1 + t2; r1 = MLP_s1(y1); y2 = e(s1)*x2 + t1.
//
// Round 8: R5 flow + in-lane epilogue (interleaved W3 perm), NO asm fences
// (sched_barrier(0) after weight loads instead of PIN), h [64][256B] with
// XOR (r&7)<<4 (structurally optimal 8-way b128), precomputed LDS slots,
// x2 packed once in phase A (planes [64][80B], 8-way-balanced reads).
// 7 barriers; LDS 32KB; LB(256,4).
//
// MFMA v_mfma_f32_16x16x32_bf16, W = A-operand, activations = B-operand:
//   A frag: lane l holds A[row=l&15][k=(l>>4)*8+j]
//   B frag: lane l holds B[k=(l>>4)*8+j][col=l&15]
//   D     : lane l reg i -> (A-row = 4*(l>>4)+i, col = l&15)  [m89/m91]

using bf16x8 = __attribute__((ext_vector_type(8))) short;
using f32x4  = __attribute__((ext_vector_type(4))) float;
using u32x2  = __attribute__((ext_vector_type(2))) unsigned int;

__device__ __forceinline__ unsigned short f2bf(float f) {
    unsigned int u = __float_as_uint(f);
    u += 0x7FFFu + ((u >> 16) & 1u);
    return (unsigned short)(u >> 16);
}
__device__ __forceinline__ unsigned int pk2bf(float a, float b) {
    union { __hip_bfloat162 h; unsigned int u; } cv;
    cv.h = __float22bfloat162_rn(float2{a, b});
    return cv.u;   // low16 = bf16(a), high16 = bf16(b)
}
__device__ __forceinline__ float lo16f(unsigned int u) { return __uint_as_float(u << 16); }
__device__ __forceinline__ float hi16f(unsigned int u) { return __uint_as_float(u & 0xFFFF0000u); }

__device__ __forceinline__ f32x4 mfma16(bf16x8 a, bf16x8 b, f32x4 c) {
    return __builtin_amdgcn_mfma_f32_16x16x32_bf16(a, b, c, 0, 0, 0);
}

// e(s) = exp(3.18*atan(s/5)) = exp2(4.5877702*atan(0.2 s)); deg-11 minimax.
__device__ __forceinline__ float e_fun(float s) {
    float z = 0.2f * s;
    float a = fabsf(z);
    float t = fminf(a, __builtin_amdgcn_rcpf(a));   // a<=1 ? a : 1/a
    float u = t * t;
    float p = -0.0537741f;
    p = fmaf(p, u,  0.2415614f);
    p = fmaf(p, u, -0.5341673f);
    p = fmaf(p, u,  0.8879339f);
    p = fmaf(p, u, -1.5260000f);
    p = fmaf(p, u,  4.5876659f);
    p = p * t;
    float r = (a > 1.0f) ? (7.2064613f - p) : p;    // K*pi/2 - p
    r = copysignf(r, s);
    return __builtin_amdgcn_exp2f(r);
}

// W3 interleaved permutation: wave w, frag-row fr = 4q+i ->
//   i<2: s-feature 8w+2q+i ; i>=2: t-feature 32+8w+2q+(i-2)
__device__ __forceinline__ int feat3b(int w, int fr) {
    int q = fr >> 2, i = fr & 3;
    int base = 8 * w + 2 * q;
    return (i < 2) ? (base + i) : (32 + base + (i - 2));
}

// LDS: h1 [64][256B] @0 (16384); h2 [64][256B] @16384.
// planes (hi [64][80B] + lo [64][80B]) time-share h2[0:10240].
#define LDS_BYTES 32768

#define BIAS_OFF 114688           // 112 tiles * 1024B
#define WS_NEED  (114688 + 2560)

struct WPtrs { const float *w1, *b1, *w2, *b2, *w3, *b3; };

__device__ __forceinline__ bf16x8 load_wfrag(const float* __restrict__ W, int K, int frow, int k0) {
    const float4* p = reinterpret_cast<const float4*>(W + (size_t)frow * K + k0);
    float4 a = p[0], b = p[1];
    bf16x8 r;
    r[0] = (short)f2bf(a.x); r[1] = (short)f2bf(a.y);
    r[2] = (short)f2bf(a.z); r[3] = (short)f2bf(a.w);
    r[4] = (short)f2bf(b.x); r[5] = (short)f2bf(b.y);
    r[6] = (short)f2bf(b.z); r[7] = (short)f2bf(b.w);
    return r;
}

template<int MODE>
__device__ __forceinline__ bf16x8 get_frag(const char* wsb, const WPtrs& P, int mlp,
                                           int tile, int which, int row, int k0, int lane) {
    if constexpr (MODE != 0) {
        union { uint4 q; bf16x8 v; } u;
        u.q = reinterpret_cast<const uint4*>(wsb)[(mlp * 56 + tile) * 64 + lane];
        return u.v;
    } else {
        const float* W = (which == 0) ? P.w1 : (which == 1) ? P.w2 : P.w3;
        return load_wfrag(W, (which == 0) ? 32 : 128, row, k0);
    }
}

__device__ __forceinline__ f32x4 ld4(const float* p) {
    return *reinterpret_cast<const f32x4*>(p);
}

// ---- one 3-layer MLP over the 64-row tile, 4-wave f-split ----
// L1 input from planes ph/pl ([64][80B] hi/lo bf16).
// rr[m] regs: i<2 -> s at col 8w+2lg+i ; i>=2 -> t at col 8w+2lg+(i-2).
template<int MODE>
__device__ __forceinline__ void run_mlp(
    const char* __restrict__ wsb, const WPtrs& P, int mlp,
    const char* __restrict__ ph, const char* __restrict__ pl,
    char* __restrict__ h1, char* __restrict__ h2,
    int w, int lg, int lr, int lane, f32x4 (&rr)[4])
{
    const int sw = (lr & 7) << 4;
    const float* bias = reinterpret_cast<const float*>(wsb + BIAS_OFF) + mlp * 320;

    // precomputed LDS slots (loop-invariant)
    int rslot[4];
    #pragma unroll
    for (int ks = 0; ks < 4; ++ks) rslot[ks] = (64 * ks + 16 * lg) ^ sw;
    const int wslot0 = (32 * (2 * w + 0) + 8 * lg) ^ sw;
    const int wslot1 = (32 * (2 * w + 1) + 8 * lg) ^ sw;
    const int pbase  = lr * 80 + 16 * lg;   // plane-read base (row lr)

    // ---------- layer 1: K=32 (hi+lo), wave's tiles ft = 2w, 2w+1 ----------
    bf16x8 wb1[2]; f32x4 b1v[2];
    #pragma unroll
    for (int f = 0; f < 2; ++f) {
        const int ft = 2 * w + f;
        wb1[f] = get_frag<MODE>(wsb, P, mlp, ft, 0, 16 * ft + lr, 8 * lg, lane);
        b1v[f] = MODE ? ld4(bias + 16 * ft + 4 * lg) : ld4(P.b1 + 16 * ft + 4 * lg);
    }
    __builtin_amdgcn_sched_barrier(0);   // keep loads batched above the loop
    #pragma unroll
    for (int m = 0; m < 4; ++m) {
        const int r = 16 * m + lr;
        bf16x8 bh = *reinterpret_cast<const bf16x8*>(ph + pbase + m * 1280);
        bf16x8 bl = *reinterpret_cast<const bf16x8*>(pl + pbase + m * 1280);
        #pragma unroll
        for (int f = 0; f < 2; ++f) {
            f32x4 acc = b1v[f];
            acc = mfma16(wb1[f], bh, acc);
            acc = mfma16(wb1[f], bl, acc);
            u32x2 pp = { pk2bf(fmaxf(acc[0], 0.f), fmaxf(acc[1], 0.f)),
                         pk2bf(fmaxf(acc[2], 0.f), fmaxf(acc[3], 0.f)) };
            *reinterpret_cast<u32x2*>(h1 + r * 256 + (f ? wslot1 : wslot0)) = pp;
        }
    }
    __syncthreads();

    // ---------- layer 2: K=128 ----------
    bf16x8 wb2[2][4]; f32x4 b2v[2];
    #pragma unroll
    for (int f = 0; f < 2; ++f) {
        const int ft = 2 * w + f;
        #pragma unroll
        for (int ks = 0; ks < 4; ++ks)
            wb2[f][ks] = get_frag<MODE>(wsb, P, mlp, 8 + ft * 4 + ks, 1,
                                        16 * ft + lr, 32 * ks + 8 * lg, lane);
        b2v[f] = MODE ? ld4(bias + 128 + 16 * ft + 4 * lg) : ld4(P.b2 + 16 * ft + 4 * lg);
    }
    __builtin_amdgcn_sched_barrier(0);
    #pragma unroll
    for (int m = 0; m < 4; ++m) {
        const int r = 16 * m + lr;
        const char* rowp = h1 + r * 256;
        bf16x8 hf[4];
        #pragma unroll
        for (int ks = 0; ks < 4; ++ks)
            hf[ks] = *reinterpret_cast<const bf16x8*>(rowp + rslot[ks]);
        #pragma unroll
        for (int f = 0; f < 2; ++f) {
            f32x4 acc = b2v[f];
            #pragma unroll
            for (int ks = 0; ks < 4; ++ks)
                acc = mfma16(wb2[f][ks], hf[ks], acc);
            u32x2 pp = { pk2bf(fmaxf(acc[0], 0.f), fmaxf(acc[1], 0.f)),
                         pk2bf(fmaxf(acc[2], 0.f), fmaxf(acc[3], 0.f)) };
            *reinterpret_cast<u32x2*>(h2 + r * 256 + (f ? wslot1 : wslot0)) = pp;
        }
    }
    __syncthreads();

    // ---------- layer 3: K=128, interleaved s/t features ----------
    bf16x8 wb3[4];
    #pragma unroll
    for (int ks = 0; ks < 4; ++ks)
        wb3[ks] = get_frag<MODE>(wsb, P, mlp, 40 + 4 * w + ks, 2,
                                 feat3b(w, lr), 32 * ks + 8 * lg, lane);
    f32x4 b3v;
    if (MODE) {
        b3v = ld4(bias + 256 + 16 * w + 4 * lg);
    } else {
        float2 sa = *reinterpret_cast<const float2*>(P.b3 + 8 * w + 2 * lg);
        float2 sb = *reinterpret_cast<const float2*>(P.b3 + 32 + 8 * w + 2 * lg);
        b3v = f32x4{sa.x, sa.y, sb.x, sb.y};
    }
    __builtin_amdgcn_sched_barrier(0);
    #pragma unroll
    for (int m = 0; m < 4; ++m) {
        const int r = 16 * m + lr;
        const char* rowp = h2 + r * 256;
        f32x4 acc = b3v;
        #pragma unroll
        for (int ks = 0; ks < 4; ++ks) {
            bf16x8 hg = *reinterpret_cast<const bf16x8*>(rowp + rslot[ks]);
            acc = mfma16(wb3[ks], hg, acc);
        }
        rr[m] = acc;
    }
}

// ---- weight prep: fragment tiles (1KB each) + biases (b3 permuted) ----
extern "C" __global__ void __launch_bounds__(256)
glow_prep(const float* __restrict__ s2w1, const float* __restrict__ s2w2,
          const float* __restrict__ s2w3, const float* __restrict__ s1w1,
          const float* __restrict__ s1w2, const float* __restrict__ s1w3,
          const float* __restrict__ s2b1, const float* __restrict__ s2b2,
          const float* __restrict__ s2b3, const float* __restrict__ s1b1,
          const float* __restrict__ s1b2, const float* __restrict__ s1b3,
          char* __restrict__ wsb)
{
    const int wave = threadIdx.x >> 6, lane = threadIdx.x & 63;
    const int lr = lane & 15, lg = lane >> 4;
    const int gw = blockIdx.x * 4 + wave;

    if (gw < 112) {
        int mlp = gw / 56, t = gw % 56;
        const float* Ws[2][3] = {{s2w1, s2w2, s2w3}, {s1w1, s1w2, s1w3}};
        const float* W; int K, row, k0;
        if (t < 8)       { W = Ws[mlp][0]; K = 32;  row = 16 * t + lr;          k0 = lg * 8; }
        else if (t < 40) { int u = t - 8;  W = Ws[mlp][1]; K = 128; row = 16 * (u >> 2) + lr; k0 = 32 * (u & 3) + lg * 8; }
        else             { int u = t - 40; W = Ws[mlp][2]; K = 128; row = feat3b(u >> 2, lr); k0 = 32 * (u & 3) + lg * 8; }
        const float* p = W + (size_t)row * K + k0;
        union U { uint4 q; bf16x8 v; } u;
        #pragma unroll
        for (int j = 0; j < 8; ++j) u.v[j] = (short)f2bf(p[j]);
        reinterpret_cast<uint4*>(wsb)[gw * 64 + lane] = u.q;
    } else if (blockIdx.x == 28) {
        const float* Bs[2][3] = {{s2b1, s2b2, s2b3}, {s1b1, s1b2, s1b3}};
        float* dst = reinterpret_cast<float*>(wsb + BIAS_OFF);
        for (int i = threadIdx.x; i < 640; i += 256) {
            int mlp = i / 320, j = i % 320;
            float v;
            if (j < 128)      v = Bs[mlp][0][j];
            else if (j < 256) v = Bs[mlp][1][j - 128];
            else { int k = j - 256; v = Bs[mlp][2][feat3b(k >> 4, k & 15)]; }
            dst[i] = v;
        }
    }
}

template<int MODE>
__global__ void __launch_bounds__(256, 4)
glow_main(const float* __restrict__ x,
          const float* __restrict__ s1w1, const float* __restrict__ s1b1,
          const float* __restrict__ s1w2, const float* __restrict__ s1b2,
          const float* __restrict__ s1w3, const float* __restrict__ s1b3,
          const float* __restrict__ s2w1, const float* __restrict__ s2b1,
          const float* __restrict__ s2w2, const float* __restrict__ s2b2,
          const float* __restrict__ s2w3, const float* __restrict__ s2b3,
          const char* __restrict__ wsb, float* __restrict__ out)
{
    __shared__ __align__(16) char lds[LDS_BYTES];
    char* h1 = lds;
    char* h2 = lds + 16384;
    char* ph = h2;             // planes hi [64][80B], time-share h2
    char* pl = h2 + 5120;      // planes lo

    const int tid  = threadIdx.x;
    const int w = tid >> 6, lane = tid & 63;
    const int lr = lane & 15, lg = lane >> 4;
    const size_t rowbase = (size_t)blockIdx.x * 64;
    const float* gx = x   + rowbase * 64;
    float*       go = out + rowbase * 64;

    const WPtrs P0 = {s2w1, s2b1, s2w2, s2b2, s2w3, s2b3};
    const WPtrs P1 = {s1w1, s1b1, s1w2, s1b2, s1w3, s1b3};

    const int c0 = 8 * w + 2 * lg;
    f32x4 rr[4];

    // ---- Phase A: pack x2 -> hi/lo planes (each element handled once) ----
    #pragma unroll
    for (int it = 0; it < 2; ++it) {
        int chunk = it * 256 + tid;          // 512 chunks of 4 floats
        int r = chunk >> 3, c4 = (chunk & 7) * 4;
        f32x4 v = *reinterpret_cast<const f32x4*>(gx + (size_t)r * 64 + 32 + c4);
        unsigned int h0 = pk2bf(v[0], v[1]), h1p = pk2bf(v[2], v[3]);
        unsigned int l0 = pk2bf(v[0] - lo16f(h0),  v[1] - hi16f(h0));
        unsigned int l1 = pk2bf(v[2] - lo16f(h1p), v[3] - hi16f(h1p));
        *reinterpret_cast<u32x2*>(ph + r * 80 + 2 * c4) = u32x2{h0, h1p};
        *reinterpret_cast<u32x2*>(pl + r * 80 + 2 * c4) = u32x2{l0, l1};
    }
    __syncthreads();                                  // (1)

    // ---- MLP s2 on x2 (2 internal barriers) ----
    run_mlp<MODE>(wsb, P0, 0, ph, pl, h1, h2, w, lg, lr, lane, rr);
    __syncthreads();   // (4) h2 reads done before plane overwrite

    // ---- epilogue 1: y1 = e(s2)*x1 + t2 -> out cols 0..31 + y1 planes ----
    #pragma unroll
    for (int m = 0; m < 4; ++m) {
        const int r = 16 * m + lr;
        float2 xv = *reinterpret_cast<const float2*>(gx + (size_t)r * 64 + c0);
        float y0 = fmaf(e_fun(rr[m][0]), xv.x, rr[m][2]);
        float y1 = fmaf(e_fun(rr[m][1]), xv.y, rr[m][3]);
        *reinterpret_cast<float2*>(go + (size_t)r * 64 + c0) = float2{y0, y1};
        unsigned int hh = pk2bf(y0, y1);
        unsigned int ll = pk2bf(y0 - lo16f(hh), y1 - hi16f(hh));
        *reinterpret_cast<unsigned int*>(ph + r * 80 + 2 * c0) = hh;
        *reinterpret_cast<unsigned int*>(pl + r * 80 + 2 * c0) = ll;
    }
    __syncthreads();                                  // (5)

    // ---- MLP s1 on y1 (2 internal barriers) ----
    run_mlp<MODE>(wsb, P1, 1, ph, pl, h1, h2, w, lg, lr, lane, rr);

    // ---- epilogue 2: y2 = e(s1)*x2 + t1 -> out cols 32..63 (no LDS) ----
    #pragma unroll
    for (int m = 0; m < 4; ++m) {
        const int r = 16 * m + lr;
        float2 xv = *reinterpret_cast<const float2*>(gx + (size_t)r * 64 + 32 + c0);
        float y0 = fmaf(e_fun(rr[m][0]), xv.x, rr[m][2]);
        float y1 = fmaf(e_fun(rr[m][1]), xv.y, rr[m][3]);
        *reinterpret_cast<float2*>(go + (size_t)r * 64 + 32 + c0) = float2{y0, y1};
    }
}

extern "C" void kernel_launch(void* const* d_in, const int* in_sizes, int n_in,
                              void* d_out, int out_size, void* d_ws, size_t ws_size,
                              hipStream_t stream) {
    const float* x    = (const float*)d_in[0];
    const float* s1w1 = (const float*)d_in[1];
    const float* s1b1 = (const float*)d_in[2];
    const float* s1w2 = (const float*)d_in[3];
    const float* s1b2 = (const float*)d_in[4];
    const float* s1w3 = (const float*)d_in[5];
    const float* s1b3 = (const float*)d_in[6];
    const float* s2w1 = (const float*)d_in[7];
    const float* s2b1 = (const float*)d_in[8];
    const float* s2w2 = (const float*)d_in[9];
    const float* s2b2 = (const float*)d_in[10];
    const float* s2w3 = (const float*)d_in[11];
    const float* s2b3 = (const float*)d_in[12];
    float* out = (float*)d_out;
    char* wsb  = (char*)d_ws;

    int nrows   = in_sizes[0] / 64;   // 262144
    int nblocks = nrows / 64;         // 4096

    if (ws_size >= (size_t)WS_NEED) {
        hipLaunchKernelGGL(glow_prep, dim3(29), dim3(256), 0, stream,
                           s2w1, s2w2, s2w3, s1w1, s1w2, s1w3,
                           s2b1, s2b2, s2b3, s1b1, s1b2, s1b3, wsb);
        hipLaunchKernelGGL((glow_main<1>), dim3(nblocks), dim3(256), 0, stream,
                           x, s1w1, s1b1, s1w2, s1b2, s1w3, s1b3,
                           s2w1, s2b1, s2w2, s2b2, s2w3, s2b3, wsb, out);
    } else {
        hipLaunchKernelGGL((glow_main<0>), dim3(nblocks), dim3(256), 0, stream,
                           x, s1w1, s1b1, s1w2, s1b2, s1w3, s1b3,
                           s2w1, s2b1, s2w2, s2b2, s2w3, s2b3, wsb, out);
    }
}